// Round 1
// baseline (179.146 us; speedup 1.0000x reference)
//
#include <hip/hip_runtime.h>

// Lennard-Jones per-edge energy + scatter-sum onto center atoms.
// Inputs (dict order):
//  0 sigma   [16,16] f32    1 delta [16,16] f32   2 epsilon [16,16] f32
//  3 edge_len [E] f32       4 edge_cutoff [E] f32
//  5 edge_index [2,E] int32 (harness converts int64 -> int32)
//  6 atom_types [N] int32
// Output: [N,1] f32 per-atom energy.

__global__ __launch_bounds__(256) void lj_scatter_kernel(
    const float* __restrict__ sigma,
    const float* __restrict__ delta,
    const float* __restrict__ epsilon,
    const float* __restrict__ edge_len,
    const float* __restrict__ edge_cutoff,
    const int*  __restrict__ edge_index,   // [2, E] flat: center = [e], other = [E + e]
    const int*  __restrict__ atom_types,   // [N]
    float* __restrict__ out,               // [N]
    int n_edges)
{
    // Symmetrize + relu the 16x16 pair tables into LDS (one entry per thread).
    __shared__ float s_sig[256];
    __shared__ float s_dlt[256];
    __shared__ float s_eps[256];
    const int t = threadIdx.x;
    {
        const int i  = t >> 4;
        const int j  = t & 15;
        const int lo = min(i, j);
        const int hi = max(i, j);
        const int src = lo * 16 + hi;          // sym[i][j] = p[min][max]
        s_sig[t] = fmaxf(sigma[src],   0.0f);  // relu
        s_dlt[t] = fmaxf(delta[src],   0.0f);
        s_eps[t] = fmaxf(epsilon[src], 0.0f);
    }
    __syncthreads();

    const int base = (blockIdx.x * 256 + t) * 4;
    if (base >= n_edges) return;

    if (base + 4 <= n_edges) {
        const int4   ctr = *reinterpret_cast<const int4*>(edge_index + base);
        const int4   oth = *reinterpret_cast<const int4*>(edge_index + n_edges + base);
        const float4 len = *reinterpret_cast<const float4*>(edge_len + base);
        const float4 cut = *reinterpret_cast<const float4*>(edge_cutoff + base);

        const int   c[4] = {ctr.x, ctr.y, ctr.z, ctr.w};
        const int   o[4] = {oth.x, oth.y, oth.z, oth.w};
        const float L[4] = {len.x, len.y, len.z, len.w};
        const float C[4] = {cut.x, cut.y, cut.z, cut.w};

        #pragma unroll
        for (int k = 0; k < 4; ++k) {
            const int flat = (atom_types[c[k]] << 4) | atom_types[o[k]];
            const float sig = s_sig[flat];
            const float dlt = s_dlt[flat];
            const float eps = s_eps[flat];
            const float r   = sig / (L[k] - dlt);
            const float r2  = r * r;
            const float x   = r2 * r2 * r2;                 // (sig/(len-dlt))^6
            const float e   = 2.0f * eps * (x * x - x) * C[k];
            atomicAdd(out + c[k], e);
        }
    } else {
        // scalar tail (not hit for E = 3.2M, kept for generality)
        for (int e = base; e < n_edges; ++e) {
            const int ci = edge_index[e];
            const int oi = edge_index[n_edges + e];
            const int flat = (atom_types[ci] << 4) | atom_types[oi];
            const float sig = s_sig[flat];
            const float dlt = s_dlt[flat];
            const float eps = s_eps[flat];
            const float r   = sig / (edge_len[e] - dlt);
            const float r2  = r * r;
            const float x   = r2 * r2 * r2;
            const float en  = 2.0f * eps * (x * x - x) * edge_cutoff[e];
            atomicAdd(out + ci, en);
        }
    }
}

extern "C" void kernel_launch(void* const* d_in, const int* in_sizes, int n_in,
                              void* d_out, int out_size, void* d_ws, size_t ws_size,
                              hipStream_t stream) {
    const float* sigma       = (const float*)d_in[0];
    const float* delta       = (const float*)d_in[1];
    const float* epsilon     = (const float*)d_in[2];
    const float* edge_len    = (const float*)d_in[3];
    const float* edge_cutoff = (const float*)d_in[4];
    const int*   edge_index  = (const int*)d_in[5];
    const int*   atom_types  = (const int*)d_in[6];
    float*       out         = (float*)d_out;

    const int n_edges = in_sizes[3];

    // Harness poisons d_out (0xAA) and does not re-poison between replays:
    // zero it every call (stream-ordered, graph-capture safe).
    hipMemsetAsync(d_out, 0, (size_t)out_size * sizeof(float), stream);

    const int threads = 256;
    const int edges_per_block = threads * 4;
    const int grid = (n_edges + edges_per_block - 1) / edges_per_block;

    lj_scatter_kernel<<<grid, threads, 0, stream>>>(
        sigma, delta, epsilon, edge_len, edge_cutoff,
        edge_index, atom_types, out, n_edges);
}

// Round 2
// 172.545 us; speedup vs baseline: 1.0383x; 1.0383x over previous
//
#include <hip/hip_runtime.h>

// Lennard-Jones per-edge energy + scatter-sum onto center atoms.
//
// R2 change: device-scope f32 atomics were memory-side (WRITE_SIZE == 3.2M x 32B,
// 18.5 G atomics/s, 173 us). Privatize into 8 per-XCD replicas in d_ws and use
// WORKGROUP-scope atomics (no SC1 -> executed in the local XCD's L2, which is
// shared by every CU on that XCD -> atomic across all blocks that can touch the
// replica). Reduce kernel sums the replicas.
//
// Inputs (dict order):
//  0 sigma   [16,16] f32    1 delta [16,16] f32   2 epsilon [16,16] f32
//  3 edge_len [E] f32       4 edge_cutoff [E] f32
//  5 edge_index [2,E] int32 6 atom_types [N] int32
// Output: [N,1] f32 per-atom energy.

#define N_XCD 8
// hwreg(id=20 HW_REG_XCC_ID, offset=0, size=32) -> imm = 20 | (0<<6) | (31<<11)
#define HWREG_XCC_ID 63508

__device__ __forceinline__ void load_tables(const float* __restrict__ sigma,
                                            const float* __restrict__ delta,
                                            const float* __restrict__ epsilon,
                                            float* s_sig, float* s_dlt, float* s_eps,
                                            int t) {
    const int i  = t >> 4;
    const int j  = t & 15;
    const int lo = min(i, j);
    const int hi = max(i, j);
    const int src = lo * 16 + hi;          // sym[i][j] = p[min][max]  (triu + triu(1).T)
    s_sig[t] = fmaxf(sigma[src],   0.0f);  // relu
    s_dlt[t] = fmaxf(delta[src],   0.0f);
    s_eps[t] = fmaxf(epsilon[src], 0.0f);
}

__device__ __forceinline__ float lj_energy(float sig, float dlt, float eps,
                                           float len, float cut) {
    const float r  = sig / (len - dlt);
    const float r2 = r * r;
    const float x  = r2 * r2 * r2;               // (sig/(len-dlt))^6
    return 2.0f * eps * (x * x - x) * cut;
}

// ---- main kernel: per-XCD privatized accumulation (workgroup-scope atomics) ----
__global__ __launch_bounds__(256) void lj_scatter_priv(
    const float* __restrict__ sigma,
    const float* __restrict__ delta,
    const float* __restrict__ epsilon,
    const float* __restrict__ edge_len,
    const float* __restrict__ edge_cutoff,
    const int*  __restrict__ edge_index,   // [2, E] flat
    const int*  __restrict__ atom_types,   // [N]
    float* __restrict__ ws_rep,            // [N_XCD, n_nodes]
    int n_edges, int n_nodes)
{
    __shared__ float s_sig[256];
    __shared__ float s_dlt[256];
    __shared__ float s_eps[256];
    const int t = threadIdx.x;
    load_tables(sigma, delta, epsilon, s_sig, s_dlt, s_eps, t);

    // XCC id: constant per CU, hence per workgroup. Mask to 0..7.
    const unsigned xcd = __builtin_amdgcn_s_getreg(HWREG_XCC_ID) & (N_XCD - 1);
    float* __restrict__ rep = ws_rep + (size_t)xcd * (size_t)n_nodes;
    __syncthreads();

    const int base = (blockIdx.x * 256 + t) * 4;
    if (base >= n_edges) return;

    if (base + 4 <= n_edges) {
        const int4   ctr = *reinterpret_cast<const int4*>(edge_index + base);
        const int4   oth = *reinterpret_cast<const int4*>(edge_index + n_edges + base);
        const float4 len = *reinterpret_cast<const float4*>(edge_len + base);
        const float4 cut = *reinterpret_cast<const float4*>(edge_cutoff + base);

        const int   c[4] = {ctr.x, ctr.y, ctr.z, ctr.w};
        const int   o[4] = {oth.x, oth.y, oth.z, oth.w};
        const float L[4] = {len.x, len.y, len.z, len.w};
        const float C[4] = {cut.x, cut.y, cut.z, cut.w};

        #pragma unroll
        for (int k = 0; k < 4; ++k) {
            const int flat = (atom_types[c[k]] << 4) | atom_types[o[k]];
            const float e = lj_energy(s_sig[flat], s_dlt[flat], s_eps[flat], L[k], C[k]);
            // No SC1 -> executes in the local XCD's TCC (L2). Atomic across the
            // whole XCD since every CU on the XCD shares this L2; only this XCD
            // ever touches rep[].
            __hip_atomic_fetch_add(rep + c[k], e, __ATOMIC_RELAXED,
                                   __HIP_MEMORY_SCOPE_WORKGROUP);
        }
    } else {
        for (int e = base; e < n_edges; ++e) {
            const int ci = edge_index[e];
            const int oi = edge_index[n_edges + e];
            const int flat = (atom_types[ci] << 4) | atom_types[oi];
            const float en = lj_energy(s_sig[flat], s_dlt[flat], s_eps[flat],
                                       edge_len[e], edge_cutoff[e]);
            __hip_atomic_fetch_add(rep + ci, en, __ATOMIC_RELAXED,
                                   __HIP_MEMORY_SCOPE_WORKGROUP);
        }
    }
}

// ---- reduce: out[n] = sum_r rep[r][n] ----
__global__ __launch_bounds__(256) void lj_reduce(
    const float* __restrict__ ws_rep, float* __restrict__ out, int n_nodes)
{
    const int n = blockIdx.x * 256 + threadIdx.x;
    if (n < n_nodes) {
        float s = 0.0f;
        #pragma unroll
        for (int r = 0; r < N_XCD; ++r)
            s += ws_rep[(size_t)r * (size_t)n_nodes + n];
        out[n] = s;
    }
}

// ---- fallback: direct device-scope atomics (used only if ws is too small) ----
__global__ __launch_bounds__(256) void lj_scatter_direct(
    const float* __restrict__ sigma,
    const float* __restrict__ delta,
    const float* __restrict__ epsilon,
    const float* __restrict__ edge_len,
    const float* __restrict__ edge_cutoff,
    const int*  __restrict__ edge_index,
    const int*  __restrict__ atom_types,
    float* __restrict__ out,
    int n_edges)
{
    __shared__ float s_sig[256];
    __shared__ float s_dlt[256];
    __shared__ float s_eps[256];
    const int t = threadIdx.x;
    load_tables(sigma, delta, epsilon, s_sig, s_dlt, s_eps, t);
    __syncthreads();

    const int base = (blockIdx.x * 256 + t) * 4;
    if (base >= n_edges) return;
    const int lim = min(base + 4, n_edges);
    for (int e = base; e < lim; ++e) {
        const int ci = edge_index[e];
        const int oi = edge_index[n_edges + e];
        const int flat = (atom_types[ci] << 4) | atom_types[oi];
        const float en = lj_energy(s_sig[flat], s_dlt[flat], s_eps[flat],
                                   edge_len[e], edge_cutoff[e]);
        atomicAdd(out + ci, en);
    }
}

extern "C" void kernel_launch(void* const* d_in, const int* in_sizes, int n_in,
                              void* d_out, int out_size, void* d_ws, size_t ws_size,
                              hipStream_t stream) {
    const float* sigma       = (const float*)d_in[0];
    const float* delta       = (const float*)d_in[1];
    const float* epsilon     = (const float*)d_in[2];
    const float* edge_len    = (const float*)d_in[3];
    const float* edge_cutoff = (const float*)d_in[4];
    const int*   edge_index  = (const int*)d_in[5];
    const int*   atom_types  = (const int*)d_in[6];
    float*       out         = (float*)d_out;

    const int n_edges = in_sizes[3];
    const int n_nodes = in_sizes[6];

    const int threads = 256;
    const int edges_per_block = threads * 4;
    const int grid = (n_edges + edges_per_block - 1) / edges_per_block;

    const size_t rep_bytes = (size_t)N_XCD * (size_t)n_nodes * sizeof(float);

    if (ws_size >= rep_bytes) {
        float* ws_rep = (float*)d_ws;
        // zero the replicas every call (harness poisons ws once; replays must
        // not accumulate across calls)
        hipMemsetAsync(ws_rep, 0, rep_bytes, stream);
        lj_scatter_priv<<<grid, threads, 0, stream>>>(
            sigma, delta, epsilon, edge_len, edge_cutoff,
            edge_index, atom_types, ws_rep, n_edges, n_nodes);
        const int rgrid = (n_nodes + threads - 1) / threads;
        lj_reduce<<<rgrid, threads, 0, stream>>>(ws_rep, out, n_nodes);
    } else {
        hipMemsetAsync(d_out, 0, (size_t)out_size * sizeof(float), stream);
        lj_scatter_direct<<<grid, threads, 0, stream>>>(
            sigma, delta, epsilon, edge_len, edge_cutoff,
            edge_index, atom_types, out, n_edges);
    }
}

// Round 3
// 82.074 us; speedup vs baseline: 2.1827x; 2.1023x over previous
//
#include <hip/hip_runtime.h>

// Lennard-Jones per-edge energy + scatter-sum onto center atoms — no global atomics.
//
// R1/R2 evidence: f32 global atomics hit a ~20 G atomic/s wall (WRITE_SIZE ==
// n_atomics*32B, dur identical with/without per-XCD privatization). R3 replaces
// the scatter with a two-kernel binning pipeline through d_ws:
//   K1: per-block counting sort of edges by node-bucket (node>>8), energy packed
//       with the node's low 8 bits into one u32; block-major contiguous writes +
//       (count,offset) aux matrix.  No global atomics, no global scan.
//   K2: one block per bucket streams the bucket's runs, ds_add_f32 into LDS,
//       writes 256 nodes. Covers every node -> no output memset needed.
//
// Inputs: 0 sigma[16,16] 1 delta[16,16] 2 epsilon[16,16] (f32)
//         3 edge_len[E] 4 edge_cutoff[E] (f32)  5 edge_index[2,E] (int32)
//         6 atom_types[N] (int32)         Output: [N,1] f32.

#define THREADS 256
#define EPT     24            // edges per thread in K1
#define EPB     (THREADS*EPT) // 6144 edges per K1 block
#define BSHIFT  8
#define BSIZE   256           // nodes per bucket
#define MAXBLK  1024          // LDS aux cache bound in K2
#define MAXBUCKET 512

__device__ __forceinline__ float lj_energy(float sig, float dlt, float eps,
                                           float len, float cut) {
    const float r  = sig / (len - dlt);
    const float r2 = r * r;
    const float x  = r2 * r2 * r2;               // (sig/(len-dlt))^6
    return 2.0f * eps * (x * x - x) * cut;
}

__device__ __forceinline__ void load_tables(const float* __restrict__ sigma,
                                            const float* __restrict__ delta,
                                            const float* __restrict__ epsilon,
                                            float* s_sig, float* s_dlt, float* s_eps,
                                            int t) {
    const int i  = t >> 4;
    const int j  = t & 15;
    const int lo = min(i, j);
    const int hi = max(i, j);
    const int src = lo * 16 + hi;          // sym = triu(p) + triu(p,1).T
    s_sig[t] = fmaxf(sigma[src],   0.0f);  // relu
    s_dlt[t] = fmaxf(delta[src],   0.0f);
    s_eps[t] = fmaxf(epsilon[src], 0.0f);
}

// ---------------- K1: compute energy + block-local counting sort by bucket ----
__global__ __launch_bounds__(THREADS) void lj_bin_kernel(
    const float* __restrict__ sigma,
    const float* __restrict__ delta,
    const float* __restrict__ epsilon,
    const float* __restrict__ edge_len,
    const float* __restrict__ edge_cutoff,
    const int*  __restrict__ edge_index,     // [2,E] flat
    const int*  __restrict__ atom_types,     // [N]
    uint32_t* __restrict__ pairs,            // [nblk*EPB] packed (energy|local)
    int2*     __restrict__ aux,              // [nbucket][nblk] (count, offset)
    int n_edges, int nbucket, int nblk)
{
    __shared__ float s_sig[256], s_dlt[256], s_eps[256];
    __shared__ uint32_t hist[MAXBUCKET];
    __shared__ uint32_t base_[MAXBUCKET];
    __shared__ uint32_t s2[THREADS], sc[THREADS];
    __shared__ uint32_t stage[EPB];

    const int t = threadIdx.x;
    load_tables(sigma, delta, epsilon, s_sig, s_dlt, s_eps, t);
    hist[t] = 0u;
    hist[t + 256] = 0u;
    __syncthreads();

    const int blk     = blockIdx.x;
    const int blkbase = blk * EPB;

    uint32_t pk[EPT];
    int      bk[EPT];

    #pragma unroll
    for (int i = 0; i < EPT / 4; ++i) {
        const int g = blkbase + i * (THREADS * 4) + t * 4;
        if (g + 3 < n_edges) {
            const int4   ctr = *reinterpret_cast<const int4*>(edge_index + g);
            const int4   oth = *reinterpret_cast<const int4*>(edge_index + n_edges + g);
            const float4 len = *reinterpret_cast<const float4*>(edge_len + g);
            const float4 cut = *reinterpret_cast<const float4*>(edge_cutoff + g);
            const int   c[4] = {ctr.x, ctr.y, ctr.z, ctr.w};
            const int   o[4] = {oth.x, oth.y, oth.z, oth.w};
            const float L[4] = {len.x, len.y, len.z, len.w};
            const float C[4] = {cut.x, cut.y, cut.z, cut.w};
            #pragma unroll
            for (int k = 0; k < 4; ++k) {
                const int flat = (atom_types[c[k]] << 4) | atom_types[o[k]];
                const float e  = lj_energy(s_sig[flat], s_dlt[flat], s_eps[flat],
                                           L[k], C[k]);
                // pack: energy with low-8 mantissa bits replaced by node&255
                pk[i*4+k] = (__float_as_uint(e) & ~255u) | (uint32_t)(c[k] & 255);
                bk[i*4+k] = c[k] >> BSHIFT;
                atomicAdd(&hist[bk[i*4+k]], 1u);
            }
        } else {
            #pragma unroll
            for (int k = 0; k < 4; ++k) {
                const int e_idx = g + k;
                if (e_idx < n_edges) {
                    const int ci = edge_index[e_idx];
                    const int oi = edge_index[n_edges + e_idx];
                    const int flat = (atom_types[ci] << 4) | atom_types[oi];
                    const float e  = lj_energy(s_sig[flat], s_dlt[flat], s_eps[flat],
                                               edge_len[e_idx], edge_cutoff[e_idx]);
                    pk[i*4+k] = (__float_as_uint(e) & ~255u) | (uint32_t)(ci & 255);
                    bk[i*4+k] = ci >> BSHIFT;
                    atomicAdd(&hist[bk[i*4+k]], 1u);
                } else {
                    bk[i*4+k] = -1;
                }
            }
        }
    }
    __syncthreads();

    // exclusive scan of hist[0..511] with 256 threads (pair trick)
    s2[t] = hist[2*t] + hist[2*t + 1];
    sc[t] = s2[t];
    for (int off = 1; off < THREADS; off <<= 1) {
        __syncthreads();
        const uint32_t v = (t >= off) ? sc[t - off] : 0u;
        __syncthreads();
        sc[t] += v;
    }
    __syncthreads();
    const uint32_t excl = sc[t] - s2[t];
    base_[2*t]     = excl;
    base_[2*t + 1] = excl + hist[2*t];
    __syncthreads();

    // aux matrix [bucket][blk]: (count, block-local offset)
    for (int bb = t; bb < nbucket; bb += THREADS)
        aux[(size_t)bb * nblk + blk] = make_int2((int)hist[bb], (int)base_[bb]);
    __syncthreads();

    // reuse hist as scatter cursor
    hist[2*t]     = base_[2*t];
    hist[2*t + 1] = base_[2*t + 1];
    __syncthreads();

    #pragma unroll
    for (int j = 0; j < EPT; ++j) {
        if (bk[j] >= 0) {
            const uint32_t r = atomicAdd(&hist[bk[j]], 1u);
            stage[r] = pk[j];
        }
    }
    __syncthreads();

    const int nval = min(EPB, n_edges - blkbase);
    for (int i = t; i < nval; i += THREADS)
        pairs[(size_t)blk * EPB + i] = stage[i];
}

// ---------------- K2: per-bucket gather + LDS accumulate ----------------------
__global__ __launch_bounds__(THREADS) void lj_gather_kernel(
    const uint32_t* __restrict__ pairs,
    const int2*     __restrict__ aux,
    float* __restrict__ out,
    int n_nodes, int nblk)
{
    __shared__ float acc[4][BSIZE];
    __shared__ int2  cof[MAXBLK];

    const int t = threadIdx.x;
    const int b = blockIdx.x;

    #pragma unroll
    for (int w = 0; w < 4; ++w) acc[w][t] = 0.0f;
    for (int i = t; i < nblk; i += THREADS)
        cof[i] = aux[(size_t)b * nblk + i];
    __syncthreads();

    const int wave = t >> 6;
    const int lane = t & 63;
    const int grp  = lane >> 4;     // 4 groups of 16 lanes per wave
    const int lig  = lane & 15;
    const int s    = wave * 4 + grp; // 16 parallel run-streams per block

    for (int blk = s; blk < nblk; blk += 16) {
        const int cnt = cof[blk].x;
        const int off = cof[blk].y;
        for (int j = lig; j < cnt; j += 16) {
            const uint32_t p = pairs[(size_t)blk * EPB + off + j];
            atomicAdd(&acc[wave][p & 255u], __uint_as_float(p & ~255u));
        }
    }
    __syncthreads();

    const long long n = (long long)b * BSIZE + t;
    if (n < n_nodes)
        out[n] = acc[0][t] + acc[1][t] + acc[2][t] + acc[3][t];
}

// ---------------- fallback: direct device-scope atomics -----------------------
__global__ __launch_bounds__(THREADS) void lj_scatter_direct(
    const float* __restrict__ sigma,
    const float* __restrict__ delta,
    const float* __restrict__ epsilon,
    const float* __restrict__ edge_len,
    const float* __restrict__ edge_cutoff,
    const int*  __restrict__ edge_index,
    const int*  __restrict__ atom_types,
    float* __restrict__ out,
    int n_edges)
{
    __shared__ float s_sig[256], s_dlt[256], s_eps[256];
    const int t = threadIdx.x;
    load_tables(sigma, delta, epsilon, s_sig, s_dlt, s_eps, t);
    __syncthreads();

    const int base = (blockIdx.x * THREADS + t) * 4;
    if (base >= n_edges) return;
    const int lim = min(base + 4, n_edges);
    for (int e = base; e < lim; ++e) {
        const int ci = edge_index[e];
        const int oi = edge_index[n_edges + e];
        const int flat = (atom_types[ci] << 4) | atom_types[oi];
        const float en = lj_energy(s_sig[flat], s_dlt[flat], s_eps[flat],
                                   edge_len[e], edge_cutoff[e]);
        atomicAdd(out + ci, en);
    }
}

extern "C" void kernel_launch(void* const* d_in, const int* in_sizes, int n_in,
                              void* d_out, int out_size, void* d_ws, size_t ws_size,
                              hipStream_t stream) {
    const float* sigma       = (const float*)d_in[0];
    const float* delta       = (const float*)d_in[1];
    const float* epsilon     = (const float*)d_in[2];
    const float* edge_len    = (const float*)d_in[3];
    const float* edge_cutoff = (const float*)d_in[4];
    const int*   edge_index  = (const int*)d_in[5];
    const int*   atom_types  = (const int*)d_in[6];
    float*       out         = (float*)d_out;

    const int n_edges = in_sizes[3];
    const int n_nodes = in_sizes[6];

    const int nblk    = (n_edges + EPB - 1) / EPB;
    const int nbucket = (n_nodes + BSIZE - 1) / BSIZE;

    const size_t pairs_bytes = (size_t)nblk * EPB * sizeof(uint32_t); // 8B-mult
    const size_t aux_bytes   = (size_t)nbucket * nblk * sizeof(int2);
    const size_t need        = pairs_bytes + aux_bytes;

    if (ws_size >= need && nbucket <= MAXBUCKET && nblk <= MAXBLK) {
        uint32_t* pairs = (uint32_t*)d_ws;
        int2*     aux   = (int2*)((char*)d_ws + pairs_bytes);

        lj_bin_kernel<<<nblk, THREADS, 0, stream>>>(
            sigma, delta, epsilon, edge_len, edge_cutoff,
            edge_index, atom_types, pairs, aux, n_edges, nbucket, nblk);

        lj_gather_kernel<<<nbucket, THREADS, 0, stream>>>(
            pairs, aux, out, n_nodes, nblk);
    } else {
        hipMemsetAsync(d_out, 0, (size_t)out_size * sizeof(float), stream);
        const int grid = (n_edges + THREADS * 4 - 1) / (THREADS * 4);
        lj_scatter_direct<<<grid, THREADS, 0, stream>>>(
            sigma, delta, epsilon, edge_len, edge_cutoff,
            edge_index, atom_types, out, n_edges);
    }
}

// Round 4
// 68.444 us; speedup vs baseline: 2.6174x; 1.1991x over previous
//
#include <hip/hip_runtime.h>

// Lennard-Jones per-edge energy + scatter-sum — no global atomics.
//
// R3 evidence: binning pipeline beats the ~20 G/s global-atomic wall (172->82us),
// but K1/K2 are latency-bound at 14% occupancy (too few blocks, 33.8KB LDS).
// R4: more, smaller blocks. K1: EPT 24->12 (1042 blocks, 21.5KB LDS). K2: 2D grid
// (bucket x CH chunks) writing partials; K3 reduces chunks. CH chosen from ws_size.
//
// Inputs: 0 sigma[16,16] 1 delta[16,16] 2 epsilon[16,16] (f32)
//         3 edge_len[E] 4 edge_cutoff[E] (f32)  5 edge_index[2,E] (int32)
//         6 atom_types[N] (int32)         Output: [N,1] f32.

#define THREADS 256
#define EPT     12            // edges per thread in K1
#define EPB     (THREADS*EPT) // 3072 edges per K1 block
#define BSHIFT  8
#define BSIZE   256           // nodes per bucket
#define MAXBLK  2048
#define MAXBUCKET 512

__device__ __forceinline__ float lj_energy(float sig, float dlt, float eps,
                                           float len, float cut) {
    const float r  = sig / (len - dlt);
    const float r2 = r * r;
    const float x  = r2 * r2 * r2;               // (sig/(len-dlt))^6
    return 2.0f * eps * (x * x - x) * cut;
}

__device__ __forceinline__ void load_tables(const float* __restrict__ sigma,
                                            const float* __restrict__ delta,
                                            const float* __restrict__ epsilon,
                                            float* s_sig, float* s_dlt, float* s_eps,
                                            int t) {
    const int i  = t >> 4;
    const int j  = t & 15;
    const int lo = min(i, j);
    const int hi = max(i, j);
    const int src = lo * 16 + hi;          // sym = triu(p) + triu(p,1).T
    s_sig[t] = fmaxf(sigma[src],   0.0f);  // relu
    s_dlt[t] = fmaxf(delta[src],   0.0f);
    s_eps[t] = fmaxf(epsilon[src], 0.0f);
}

// ---------------- K1: energy + block-local counting sort by bucket ------------
__global__ __launch_bounds__(THREADS, 6) void lj_bin_kernel(
    const float* __restrict__ sigma,
    const float* __restrict__ delta,
    const float* __restrict__ epsilon,
    const float* __restrict__ edge_len,
    const float* __restrict__ edge_cutoff,
    const int*  __restrict__ edge_index,     // [2,E] flat
    const int*  __restrict__ atom_types,     // [N]
    uint32_t* __restrict__ pairs,            // [nblk*EPB] packed (energy|local8)
    uint32_t* __restrict__ aux,              // [nbucket][nblk] count|offset<<16
    int n_edges, int nbucket, int nblk)
{
    __shared__ float s_sig[256], s_dlt[256], s_eps[256];
    __shared__ uint32_t hist[MAXBUCKET];
    __shared__ uint32_t base_[MAXBUCKET];
    __shared__ uint32_t s2[THREADS], sc[THREADS];
    __shared__ uint32_t stage[EPB];

    const int t = threadIdx.x;
    load_tables(sigma, delta, epsilon, s_sig, s_dlt, s_eps, t);
    hist[t] = 0u;
    hist[t + 256] = 0u;
    __syncthreads();

    const int blk     = blockIdx.x;
    const int blkbase = blk * EPB;

    uint32_t pk[EPT];
    int      bk[EPT];

    #pragma unroll
    for (int i = 0; i < EPT / 4; ++i) {
        const int g = blkbase + i * (THREADS * 4) + t * 4;
        if (g + 3 < n_edges) {
            const int4   ctr = *reinterpret_cast<const int4*>(edge_index + g);
            const int4   oth = *reinterpret_cast<const int4*>(edge_index + n_edges + g);
            const float4 len = *reinterpret_cast<const float4*>(edge_len + g);
            const float4 cut = *reinterpret_cast<const float4*>(edge_cutoff + g);
            const int   c[4] = {ctr.x, ctr.y, ctr.z, ctr.w};
            const int   o[4] = {oth.x, oth.y, oth.z, oth.w};
            const float L[4] = {len.x, len.y, len.z, len.w};
            const float C[4] = {cut.x, cut.y, cut.z, cut.w};
            #pragma unroll
            for (int k = 0; k < 4; ++k) {
                const int flat = (atom_types[c[k]] << 4) | atom_types[o[k]];
                const float e  = lj_energy(s_sig[flat], s_dlt[flat], s_eps[flat],
                                           L[k], C[k]);
                pk[i*4+k] = (__float_as_uint(e) & ~255u) | (uint32_t)(c[k] & 255);
                bk[i*4+k] = c[k] >> BSHIFT;
                atomicAdd(&hist[bk[i*4+k]], 1u);
            }
        } else {
            #pragma unroll
            for (int k = 0; k < 4; ++k) {
                const int e_idx = g + k;
                if (e_idx < n_edges) {
                    const int ci = edge_index[e_idx];
                    const int oi = edge_index[n_edges + e_idx];
                    const int flat = (atom_types[ci] << 4) | atom_types[oi];
                    const float e  = lj_energy(s_sig[flat], s_dlt[flat], s_eps[flat],
                                               edge_len[e_idx], edge_cutoff[e_idx]);
                    pk[i*4+k] = (__float_as_uint(e) & ~255u) | (uint32_t)(ci & 255);
                    bk[i*4+k] = ci >> BSHIFT;
                    atomicAdd(&hist[bk[i*4+k]], 1u);
                } else {
                    bk[i*4+k] = -1;
                }
            }
        }
    }
    __syncthreads();

    // exclusive scan of hist[0..511] (256 threads, pair trick)
    s2[t] = hist[2*t] + hist[2*t + 1];
    sc[t] = s2[t];
    for (int off = 1; off < THREADS; off <<= 1) {
        __syncthreads();
        const uint32_t v = (t >= off) ? sc[t - off] : 0u;
        __syncthreads();
        sc[t] += v;
    }
    __syncthreads();
    const uint32_t excl = sc[t] - s2[t];
    base_[2*t]     = excl;
    base_[2*t + 1] = excl + hist[2*t];
    __syncthreads();

    // aux[bucket][blk] = count | offset<<16   (EPB=3072 fits u16)
    for (int bb = t; bb < nbucket; bb += THREADS)
        aux[(size_t)bb * nblk + blk] = hist[bb] | (base_[bb] << 16);
    __syncthreads();

    // reuse hist as scatter cursor
    hist[2*t]     = base_[2*t];
    hist[2*t + 1] = base_[2*t + 1];
    __syncthreads();

    #pragma unroll
    for (int j = 0; j < EPT; ++j) {
        if (bk[j] >= 0) {
            const uint32_t r = atomicAdd(&hist[bk[j]], 1u);
            stage[r] = pk[j];
        }
    }
    __syncthreads();

    const int nval = min(EPB, n_edges - blkbase);
    for (int i = t; i < nval; i += THREADS)
        pairs[(size_t)blk * EPB + i] = stage[i];
}

// ---------------- K2: per-(bucket,chunk) gather + LDS accumulate --------------
// grid = (nbucket, CH). Writes dst[(b*CH + c)*256 + t] (CH==1: dst=out directly).
__global__ __launch_bounds__(THREADS) void lj_gather_kernel(
    const uint32_t* __restrict__ pairs,
    const uint32_t* __restrict__ aux,
    float* __restrict__ dst,
    int nblk, int bpc, long long limit)
{
    __shared__ float acc[4][BSIZE];
    __shared__ uint32_t cof[MAXBLK];

    const int t  = threadIdx.x;
    const int b  = blockIdx.x;
    const int c  = blockIdx.y;
    const int CH = gridDim.y;

    const int lo   = c * bpc;
    const int hi   = min(nblk, lo + bpc);
    const int nrun = hi - lo;

    #pragma unroll
    for (int w = 0; w < 4; ++w) acc[w][t] = 0.0f;
    for (int i = t; i < nrun; i += THREADS)
        cof[i] = aux[(size_t)b * nblk + lo + i];
    __syncthreads();

    const int wave = t >> 6;
    const int lane = t & 63;
    const int grp  = lane >> 3;      // 8 groups of 8 lanes per wave
    const int lig  = lane & 7;
    const int s    = wave * 8 + grp; // 32 parallel run-streams per block

    for (int run = s; run < nrun; run += 32) {
        const uint32_t ce  = cof[run];
        const int cnt = (int)(ce & 0xffffu);
        const int off = (int)(ce >> 16);
        const size_t gbase = (size_t)(lo + run) * EPB + off;
        for (int j = lig; j < cnt; j += 8) {
            const uint32_t p = pairs[gbase + j];
            atomicAdd(&acc[wave][p & 255u], __uint_as_float(p & ~255u));
        }
    }
    __syncthreads();

    const long long idx = ((long long)b * CH + c) * BSIZE + t;
    if (idx < limit)
        dst[idx] = acc[0][t] + acc[1][t] + acc[2][t] + acc[3][t];
}

// ---------------- K3: reduce CH chunk-partials -> out -------------------------
__global__ __launch_bounds__(THREADS) void lj_reduce_kernel(
    const float* __restrict__ partial, float* __restrict__ out,
    int n_nodes, int CH)
{
    const int n = blockIdx.x * THREADS + threadIdx.x;
    if (n < n_nodes) {
        const int b = n >> BSHIFT;
        const int i = n & (BSIZE - 1);
        float s = 0.0f;
        for (int c = 0; c < CH; ++c)
            s += partial[(((size_t)b * CH + c) << BSHIFT) + i];
        out[n] = s;
    }
}

// ---------------- fallback: direct device-scope atomics -----------------------
__global__ __launch_bounds__(THREADS) void lj_scatter_direct(
    const float* __restrict__ sigma,
    const float* __restrict__ delta,
    const float* __restrict__ epsilon,
    const float* __restrict__ edge_len,
    const float* __restrict__ edge_cutoff,
    const int*  __restrict__ edge_index,
    const int*  __restrict__ atom_types,
    float* __restrict__ out,
    int n_edges)
{
    __shared__ float s_sig[256], s_dlt[256], s_eps[256];
    const int t = threadIdx.x;
    load_tables(sigma, delta, epsilon, s_sig, s_dlt, s_eps, t);
    __syncthreads();

    const int base = (blockIdx.x * THREADS + t) * 4;
    if (base >= n_edges) return;
    const int lim = min(base + 4, n_edges);
    for (int e = base; e < lim; ++e) {
        const int ci = edge_index[e];
        const int oi = edge_index[n_edges + e];
        const int flat = (atom_types[ci] << 4) | atom_types[oi];
        const float en = lj_energy(s_sig[flat], s_dlt[flat], s_eps[flat],
                                   edge_len[e], edge_cutoff[e]);
        atomicAdd(out + ci, en);
    }
}

extern "C" void kernel_launch(void* const* d_in, const int* in_sizes, int n_in,
                              void* d_out, int out_size, void* d_ws, size_t ws_size,
                              hipStream_t stream) {
    const float* sigma       = (const float*)d_in[0];
    const float* delta       = (const float*)d_in[1];
    const float* epsilon     = (const float*)d_in[2];
    const float* edge_len    = (const float*)d_in[3];
    const float* edge_cutoff = (const float*)d_in[4];
    const int*   edge_index  = (const int*)d_in[5];
    const int*   atom_types  = (const int*)d_in[6];
    float*       out         = (float*)d_out;

    const int n_edges = in_sizes[3];
    const int n_nodes = in_sizes[6];

    const int nblk    = (n_edges + EPB - 1) / EPB;
    const int nbucket = (n_nodes + BSIZE - 1) / BSIZE;

    const size_t pairs_bytes = (size_t)nblk * EPB * sizeof(uint32_t);
    const size_t aux_bytes   = (size_t)nbucket * nblk * sizeof(uint32_t);
    const size_t need_base   = pairs_bytes + aux_bytes;

    if (nbucket <= MAXBUCKET && nblk <= MAXBLK && ws_size >= need_base) {
        uint32_t* pairs = (uint32_t*)d_ws;
        uint32_t* aux   = (uint32_t*)((char*)d_ws + pairs_bytes);

        // pick chunk count CH by available workspace for partials
        int CH = 1;
        for (int tryCH = 8; tryCH >= 2; tryCH >>= 1) {
            const size_t part = (size_t)nbucket * tryCH * BSIZE * sizeof(float);
            if (ws_size >= need_base + part) { CH = tryCH; break; }
        }

        lj_bin_kernel<<<nblk, THREADS, 0, stream>>>(
            sigma, delta, epsilon, edge_len, edge_cutoff,
            edge_index, atom_types, pairs, aux, n_edges, nbucket, nblk);

        const int bpc = (nblk + CH - 1) / CH;
        if (CH == 1) {
            // partial layout == out layout; write straight to out, guard n_nodes
            lj_gather_kernel<<<dim3(nbucket, 1), THREADS, 0, stream>>>(
                pairs, aux, out, nblk, bpc, (long long)n_nodes);
        } else {
            float* partial = (float*)((char*)d_ws + need_base);
            const long long plimit = (long long)nbucket * CH * BSIZE;
            lj_gather_kernel<<<dim3(nbucket, CH), THREADS, 0, stream>>>(
                pairs, aux, partial, nblk, bpc, plimit);
            const int rgrid = (n_nodes + THREADS - 1) / THREADS;
            lj_reduce_kernel<<<rgrid, THREADS, 0, stream>>>(
                partial, out, n_nodes, CH);
        }
    } else {
        hipMemsetAsync(d_out, 0, (size_t)out_size * sizeof(float), stream);
        const int grid = (n_edges + THREADS * 4 - 1) / (THREADS * 4);
        lj_scatter_direct<<<grid, THREADS, 0, stream>>>(
            sigma, delta, epsilon, edge_len, edge_cutoff,
            edge_index, atom_types, out, n_edges);
    }
}